// Round 6
// baseline (27.531 us; speedup 1.0000x reference)
//
#include <hip/hip_runtime.h>

// RoiPoolingConv: crop-and-resize bilinear, img (1,64,64,1024) f32, 512 ROIs,
// 7x7 pool -> out (1,512,7,7,1024) f32.
//
// FINAL (revert to R3 structure, the best measured variant: 25.57 us).
//
// Structure & why:
// - Channel-slab decomposition: 8 slabs x 128 channels, slab = blockIdx & 7.
//   Under round-robin block->XCD dispatch each XCD only gathers from its own
//   2 MB image slab -> resident in the 4 MB per-XCD L2 (52 -> 27.6 us, R1).
// - NT stores: write stream passes through L2 without evicting the slab.
// - RPB=2 -> 2048 blocks = 8 blocks/CU = 32 waves/CU, max occupancy
//   (27.0 -> 25.6 us, R3).
// - Per-ROI bilinear coords (exact reference arithmetic) precomputed once
//   into a 672 B LDS table; inner loop is 6 broadcast LDS reads + 4 gathers
//   + lerp + NT store.
//
// Measured ceiling: per-XCD L2 combined traffic (51.4 MB gather reads +
// 12.8 MB write-through) / 25.6 us ~= 2.5 TB/s/XCD ~= 1 KB/cycle -- the L2
// mixed-traffic throughput limit. Occupancy-max (R3) and ILP-doubling (R4)
// probes were both null; read amplification (4 corners/output) is structural.

#define POOLSZ 7
#define NROIS  512
#define IMG_H  64
#define IMG_W  64
#define IMG_C  1024
#define NSLAB  8
#define SLABC  (IMG_C / NSLAB)     // 128
#define CELLS  (POOLSZ * POOLSZ)   // 49
#define RPB    2                   // ROIs per block
#define UNITS  (RPB * CELLS * 32)  // 3136 float4 units per block
#define ITERS  ((UNITS + 255) / 256) // 13

typedef float fvec4 __attribute__((ext_vector_type(4)));

__global__ __launch_bounds__(256, 8) void roi_pool_kernel(
    const float* __restrict__ img,
    const int*   __restrict__ rois,
    float*       __restrict__ out)
{
    __shared__ int   sYi0[RPB][POOLSZ], sYi1[RPB][POOLSZ];
    __shared__ float sFy [RPB][POOLSZ];
    __shared__ int   sXi0[RPB][POOLSZ], sXi1[RPB][POOLSZ];
    __shared__ float sFx [RPB][POOLSZ];

    const int bid     = blockIdx.x;
    const int slab    = bid & (NSLAB - 1);     // pins slab to XCD (round-robin)
    const int roibase = (bid >> 3) * RPB;

    const int t = threadIdx.x;

    // --- setup: 28 threads compute the per-ROI, per-axis coord triples ---
    if (t < RPB * 2 * POOLSZ) {
        const int rl   = t / (2 * POOLSZ);
        const int j    = t % (2 * POOLSZ);
        const int axis = j / POOLSZ;            // 0 = y, 1 = x
        const int p    = j % POOLSZ;
        const int r    = roibase + rl;

        const int x1 = rois[r * 4 + 0];
        const int y1 = rois[r * 4 + 1];
        const int w  = rois[r * 4 + 2];
        const int h  = rois[r * 4 + 3];

        const int start = axis ? x1 : y1;
        const int lim   = axis ? IMG_W : IMG_H;
        const int ext   = axis ? w : h;
        const int eff   = min(start + ext, lim) - start;
        const float efff = (float)eff;

        // Exactly the reference arithmetic: t = (p+0.5)*eff/POOL - 0.5
        const float tq = (p + 0.5f) * efff / (float)POOLSZ - 0.5f;
        const float f0 = floorf(tq);
        const float fr = tq - f0;
        const int i0 = (int)fminf(fmaxf(f0,        0.0f), efff - 1.0f) + start;
        const int i1 = (int)fminf(fmaxf(f0 + 1.0f, 0.0f), efff - 1.0f) + start;

        if (axis == 0) { sYi0[rl][p] = i0; sYi1[rl][p] = i1; sFy[rl][p] = fr; }
        else           { sXi0[rl][p] = i0; sXi1[rl][p] = i1; sFx[rl][p] = fr; }
    }
    __syncthreads();

    // --- main loop: flat float4-unit mapping, 13 iterations ---
    #pragma unroll
    for (int it = 0; it < ITERS; ++it) {
        const int unit = it * 256 + t;
        if (unit < UNITS) {
            const int cellg = unit >> 5;          // 0..97
            const int lane  = unit & 31;          // float4 within 128-ch slab
            const int rl    = cellg / CELLS;      // 0..1
            const int cell  = cellg - rl * CELLS; // 0..48
            const int py    = cell / POOLSZ;
            const int px    = cell - py * POOLSZ;

            const int   yi0 = sYi0[rl][py];
            const int   yi1 = sYi1[rl][py];
            const float fy  = sFy [rl][py];
            const int   xi0 = sXi0[rl][px];
            const int   xi1 = sXi1[rl][px];
            const float fx  = sFx [rl][px];

            const int c = slab * SLABC + lane * 4;

            const size_t base00 = ((size_t)(yi0 * IMG_W + xi0)) * IMG_C + c;
            const size_t base01 = ((size_t)(yi0 * IMG_W + xi1)) * IMG_C + c;
            const size_t base10 = ((size_t)(yi1 * IMG_W + xi0)) * IMG_C + c;
            const size_t base11 = ((size_t)(yi1 * IMG_W + xi1)) * IMG_C + c;

            const fvec4 v00 = *reinterpret_cast<const fvec4*>(img + base00);
            const fvec4 v01 = *reinterpret_cast<const fvec4*>(img + base01);
            const fvec4 v10 = *reinterpret_cast<const fvec4*>(img + base10);
            const fvec4 v11 = *reinterpret_cast<const fvec4*>(img + base11);

            const fvec4 top = v00 + (v01 - v00) * fx;
            const fvec4 bot = v10 + (v11 - v10) * fx;
            const fvec4 o   = top + (bot - top) * fy;

            const int r = roibase + rl;
            const size_t obase = ((size_t)(r * CELLS + cell)) * IMG_C + c;
            __builtin_nontemporal_store(o, reinterpret_cast<fvec4*>(out + obase));
        }
    }
}

extern "C" void kernel_launch(void* const* d_in, const int* in_sizes, int n_in,
                              void* d_out, int out_size, void* d_ws, size_t ws_size,
                              hipStream_t stream) {
    const float* img  = (const float*)d_in[0];
    const int*   rois = (const int*)d_in[1];
    float*       out  = (float*)d_out;

    const int nblocks = (NROIS / RPB) * NSLAB;  // 2048 blocks, 256 threads
    roi_pool_kernel<<<nblocks, 256, 0, stream>>>(img, rois, out);
}